// Round 8
// baseline (238.689 us; speedup 1.0000x reference)
//
#include <hip/hip_runtime.h>

// ---------------------------------------------------------------------------
// CrossAttention: B=8, T=S=1024, E=H=768, fp32 in/out, bf16 MFMA internally.
//
// Round 17: arithmetic-intensity round. Five schedule variants all pinned at
// ~13 B/cyc/CU ingest (m102 shape effect: K=768 is the "small" regime) =>
// raise FLOPs per staged byte instead of re-scheduling.
//   - proj/outproj (M=8192): 256x128 tile, 512 thr / 8 waves (4m x 2n),
//     SINGLE-buffered 48 KB LDS (A 32K + B 16K) -> 2 blocks/CU
//     (launch_bounds(512,4): 4 waves/EU). 87 FLOP/staged-B vs 64 at 128^2.
//     r11's 256x128 failed only because dbuf-96KB forced 1 block/CU.
//   - scores/pv: r13 champion core unchanged (counted-vmcnt dbuf 128^2,
//     2 blk/CU) -- 256-row tiles would leave half the CUs idle (M=1024/batch).
//   - XCD-grouped mapping everywhere (r13, +3%); fused prep (passed r15/r16).
// Swizzle (512 thr): chunk c=h*512+tid, row r=h*64+(tid>>3), slot s=tid&7,
// src k-chunk j = s^(r&7) = (tid&7)^((tid>>3)&7); read side unchanged.
// ---------------------------------------------------------------------------

typedef __bf16 bf16x8 __attribute__((ext_vector_type(8)));
typedef float  f32x4  __attribute__((ext_vector_type(4)));

#define WAIT_VM8 __builtin_amdgcn_s_waitcnt(0x0F78)   // vmcnt(8), lgkm/exp nowait
#define WAIT_VM0 __builtin_amdgcn_s_waitcnt(0x0F70)   // vmcnt(0)
#define BAR      __builtin_amdgcn_s_barrier()

__device__ __forceinline__ unsigned short f2bf(float f) {
    unsigned int u = __float_as_uint(f);
    u += 0x7fffu + ((u >> 16) & 1u);   // RNE; inputs are finite
    return (unsigned short)(u >> 16);
}

__device__ __forceinline__ void async_copy16(const void* g, void* s) {
    __builtin_amdgcn_global_load_lds(
        (const __attribute__((address_space(1))) void*)g,
        (__attribute__((address_space(3))) void*)s, 16, 0, 0);
}

// ---------------------------------------------------------------------------
// r13 champion core: 128x128, BK=64, double-buffered, counted vmcnt(8).
// Block computes C[row0:row0+128, col0:col0+128].
__device__ __forceinline__ void gemm_core(
    const unsigned short* __restrict__ Ag,
    const unsigned short* __restrict__ Bg,
    const int K,
    float* __restrict__ Cf, unsigned short* __restrict__ Cb,
    const long ldc, const int transC, const float* __restrict__ bias,
    const float scale, const long row0, const long col0)
{
    __shared__ __align__(16) unsigned short As0[8192];   // [128][64] swizzled
    __shared__ __align__(16) unsigned short As1[8192];
    __shared__ __align__(16) unsigned short Bs0[8192];
    __shared__ __align__(16) unsigned short Bs1[8192];

    const int tid  = threadIdx.x;
    const int lane = tid & 63;
    const int quad = lane >> 4;
    const int l16  = lane & 15;
    const int wv   = tid >> 6;
    const int wm   = (wv >> 1) * 64;
    const int wn   = (wv & 1) * 64;

    const int j8 = ((lane & 7) ^ ((lane >> 3) & 7)) * 8;   // src k-offset, elems
    const int rb = wv * 32 + (lane >> 3);                  // row for h=0
    const unsigned short* sa_src = Ag + (long)rb * K + j8;
    const unsigned short* sb_src = Bg + (long)rb * K + j8;
    const int dbase = (wv * 256 + lane) * 8;               // LDS dst elems, h=0

    f32x4 acc[4][4];
#pragma unroll
    for (int i = 0; i < 4; ++i)
#pragma unroll
        for (int j = 0; j < 4; ++j)
            acc[i][j] = f32x4{0.f, 0.f, 0.f, 0.f};

    auto stage = [&](unsigned short* dA, unsigned short* dB, int k0) {
#pragma unroll
        for (int h = 0; h < 4; ++h) {
            async_copy16(sa_src + (long)(h * 8) * K + k0, &dA[dbase + h * 512]);
            async_copy16(sb_src + (long)(h * 8) * K + k0, &dB[dbase + h * 512]);
        }
    };

    auto compute = [&](const unsigned short* sA, const unsigned short* sB) {
#pragma unroll
        for (int h = 0; h < 2; ++h) {
            bf16x8 af[4], bf[4];
            const int sl = ((quad + h * 4) ^ (l16 & 7)) * 8;
#pragma unroll
            for (int i = 0; i < 4; ++i) {
                af[i] = *(const bf16x8*)&sA[(wm + i * 16 + l16) * 64 + sl];
                bf[i] = *(const bf16x8*)&sB[(wn + i * 16 + l16) * 64 + sl];
            }
#pragma unroll
            for (int i = 0; i < 4; ++i)
#pragma unroll
                for (int j = 0; j < 4; ++j)
                    acc[i][j] = __builtin_amdgcn_mfma_f32_16x16x32_bf16(
                        af[i], bf[j], acc[i][j], 0, 0, 0);
        }
    };

    const int nk = K >> 6;            // 12 or 16: even, >= 4
    stage(As0, Bs0, 0);
    stage(As1, Bs1, 64);
    int k0 = 128;

    for (int t = 0; t < nk - 2; t += 2) {
        WAIT_VM8; BAR;
        compute(As0, Bs0);
        BAR;
        stage(As0, Bs0, k0); k0 += 64;

        WAIT_VM8; BAR;
        compute(As1, Bs1);
        BAR;
        stage(As1, Bs1, k0); k0 += 64;
    }
    WAIT_VM8; BAR;
    compute(As0, Bs0);
    WAIT_VM0; BAR;
    compute(As1, Bs1);

    // epilogue: C/D layout col=lane&15, row=quad*4+reg  [m89/m91 verified]
#pragma unroll
    for (int i = 0; i < 4; ++i) {
#pragma unroll
        for (int j = 0; j < 4; ++j) {
            const long r0 = row0 + wm + i * 16 + quad * 4;
            const long c  = col0 + wn + j * 16 + l16;
            const float bb = bias ? bias[c] : 0.0f;
#pragma unroll
            for (int r = 0; r < 4; ++r) {
                const float v = acc[i][j][r] * scale + bb;
                const long rr = r0 + r;
                if (Cb) {
                    if (transC) {
                        Cb[((rr >> 10) * 768 + c) * 1024 + (rr & 1023)] = f2bf(v);
                    } else {
                        Cb[rr * ldc + c] = f2bf(v);
                    }
                } else {
                    Cf[rr * ldc + c] = v;
                }
            }
        }
    }
}

// ---------------------------------------------------------------------------
// 256x128 single-buffered core: 512 threads, 8 waves (4m x 2n), 48 KB LDS,
// 2 blocks/CU. Per K-step: sync (drain DMA) ; compute ; sync ; stage(t+1).
__device__ __forceinline__ void gemm_core256(
    const unsigned short* __restrict__ Ag,
    const unsigned short* __restrict__ Bg,
    const int K,
    float* __restrict__ Cf, unsigned short* __restrict__ Cb,
    const long ldc, const int transC, const float* __restrict__ bias,
    const float scale, const long row0, const long col0)
{
    __shared__ __align__(16) unsigned short As[16384];  // [256][64] swizzled
    __shared__ __align__(16) unsigned short Bs[8192];   // [128][64] swizzled

    const int tid  = threadIdx.x;        // 0..511
    const int lane = tid & 63;
    const int quad = lane >> 4;
    const int l16  = lane & 15;
    const int wv   = tid >> 6;           // 0..7
    const int wm   = (wv >> 1) * 64;     // 0,64,128,192
    const int wn   = (wv & 1) * 64;      // 0,64

    // staging: inst h covers chunk c = h*512 + tid; row r = h*64 + (tid>>3),
    // linear slot s = tid&7; stored k-chunk j = s ^ (r&7).
    const int j8 = ((tid & 7) ^ ((tid >> 3) & 7)) * 8;   // src k-offset, elems
    const unsigned short* a_src = Ag + (long)(tid >> 3) * K + j8;
    const unsigned short* b_src = Bg + (long)(tid >> 3) * K + j8;
    const int dofs = tid * 8;            // LDS dst elems; inst h adds h*4096

    f32x4 acc[4][4];
#pragma unroll
    for (int i = 0; i < 4; ++i)
#pragma unroll
        for (int j = 0; j < 4; ++j)
            acc[i][j] = f32x4{0.f, 0.f, 0.f, 0.f};

    // one tile = 6 DMA instructions per thread (4 A + 2 B) = 48 KB/block
    auto stage = [&](int k0) {
#pragma unroll
        for (int h = 0; h < 4; ++h)
            async_copy16(a_src + (long)(h * 64) * K + k0, &As[h * 4096 + dofs]);
#pragma unroll
        for (int h = 0; h < 2; ++h)
            async_copy16(b_src + (long)(h * 64) * K + k0, &Bs[h * 4096 + dofs]);
    };

    // 32 MFMA per wave per tile (two k-halves of 32)
    auto compute = [&]() {
#pragma unroll
        for (int h = 0; h < 2; ++h) {
            bf16x8 af[4], bf[4];
            const int sl = ((quad + h * 4) ^ (l16 & 7)) * 8;
#pragma unroll
            for (int i = 0; i < 4; ++i) {
                af[i] = *(const bf16x8*)&As[(wm + i * 16 + l16) * 64 + sl];
                bf[i] = *(const bf16x8*)&Bs[(wn + i * 16 + l16) * 64 + sl];
            }
#pragma unroll
            for (int i = 0; i < 4; ++i)
#pragma unroll
                for (int j = 0; j < 4; ++j)
                    acc[i][j] = __builtin_amdgcn_mfma_f32_16x16x32_bf16(
                        af[i], bf[j], acc[i][j], 0, 0, 0);
        }
    };

    const int nk = K >> 6;            // 12
    stage(0);
#pragma unroll 1
    for (int t = 0; t < nk; ++t) {
        __syncthreads();              // drains vmcnt -> tile t landed
        compute();
        __syncthreads();              // all waves done reading As/Bs
        if (t + 1 < nk) stage((t + 1) << 6);
    }

    // epilogue (same verified layout)
#pragma unroll
    for (int i = 0; i < 4; ++i) {
#pragma unroll
        for (int j = 0; j < 4; ++j) {
            const long r0 = row0 + wm + i * 16 + quad * 4;
            const long c  = col0 + wn + j * 16 + l16;
            const float bb = bias ? bias[c] : 0.0f;
#pragma unroll
            for (int r = 0; r < 4; ++r) {
                const float v = acc[i][j][r] * scale + bb;
                const long rr = r0 + r;
                if (Cb) {
                    if (transC) {
                        Cb[((rr >> 10) * 768 + c) * 1024 + (rr & 1023)] = f2bf(v);
                    } else {
                        Cb[rr * ldc + c] = f2bf(v);
                    }
                } else {
                    Cf[rr * ldc + c] = v;
                }
            }
        }
    }
}

// ---------------------------------------------------------------------------
// XCD-locality mapping (HW round-robins consecutive blockIdx.x over 8 XCDs).

__global__ __launch_bounds__(512, 4) void proj_qkv(
    const unsigned short* __restrict__ xb, const unsigned short* __restrict__ eb,
    const unsigned short* __restrict__ wqt, const unsigned short* __restrict__ wkt,
    const unsigned short* __restrict__ wvt,
    const float* __restrict__ bq, const float* __restrict__ bk,
    const float* __restrict__ bv,
    unsigned short* __restrict__ q, unsigned short* __restrict__ k,
    unsigned short* __restrict__ vt)
{
    const unsigned short *A, *Bt; const float* bias; unsigned short* C;
    int trans = 0;
    switch (blockIdx.z) {
        case 0:  A = xb; Bt = wqt; bias = bq; C = q;  break;
        case 1:  A = eb; Bt = wkt; bias = bk; C = k;  break;
        default: A = eb; Bt = wvt; bias = bv; C = vt; trans = 1; break;
    }
    // p in [0,192): xcd g owns row-tiles g*4..g*4+3 (256 rows each) x 6 cols:
    // A 4*256*768*2 = 1.6MB + B 1.2MB fits the XCD L2.
    const int p = blockIdx.x;
    const int g = p & 7, m = p >> 3;          // m in [0,24)
    const long row0 = (long)(g * 4 + (m & 3)) * 256;
    const long col0 = (long)(m >> 2) * 128;
    gemm_core256(A + row0 * 768, Bt + col0 * 768, 768,
                 nullptr, C, 768, trans, bias, 1.0f, row0, col0);
}

__global__ __launch_bounds__(256, 2) void scores_gemm(
    const unsigned short* __restrict__ q, const unsigned short* __restrict__ k,
    float* __restrict__ sc, float scale)
{
    const int p = blockIdx.x;                 // [0,512): batch pinned to XCD
    const long b = p & 7;
    const int m  = p >> 3;                    // [0,64)
    const long row0 = (long)(m & 7) * 128;
    const long col0 = (long)(m >> 3) * 128;
    gemm_core(q + (b * 1024 + row0) * 768, k + b * 786432 + col0 * 768, 768,
              sc + b * 1048576, nullptr, 1024, 0, nullptr, scale, row0, col0);
}

__global__ __launch_bounds__(256, 2) void pv_gemm(
    const unsigned short* __restrict__ p_, const unsigned short* __restrict__ vt,
    unsigned short* __restrict__ ao)
{
    const int p = blockIdx.x;                 // [0,384): batch pinned to XCD
    const long b = p & 7;
    const int m  = p >> 3;                    // [0,48)
    const long row0 = (long)(m & 7) * 128;
    const long col0 = (long)(m >> 3) * 128;
    gemm_core(p_ + (b * 1024 + row0) * 1024, vt + b * 786432 + col0 * 1024, 1024,
              nullptr, ao + b * 786432, 768, 0, nullptr, 1.0f, row0, col0);
}

__global__ __launch_bounds__(512, 4) void outproj_gemm(
    const unsigned short* __restrict__ ao, const unsigned short* __restrict__ wpt,
    float* __restrict__ out, const float* __restrict__ bp)
{
    const int p = blockIdx.x;                 // [0,192)
    const int g = p & 7, m = p >> 3;
    const long row0 = (long)(g * 4 + (m & 3)) * 256;
    const long col0 = (long)(m >> 2) * 128;
    gemm_core256(ao + row0 * 768, wpt + col0 * 768, 768,
                 out, nullptr, 768, 0, bp, 1.0f, row0, col0);
}

// ---------------------------------------------------------------------------
// prep: fp32->bf16 conversion of x/enc (blocks 0..12287) + 32x32 bf16
// transposes of the four weights (blocks 12288..14591).

__global__ __launch_bounds__(256) void prep(
    const float* __restrict__ x, const float* __restrict__ enc,
    unsigned short* __restrict__ xb, unsigned short* __restrict__ eb,
    const float* __restrict__ w0, const float* __restrict__ w1,
    const float* __restrict__ w2, const float* __restrict__ w3,
    unsigned short* __restrict__ o0, unsigned short* __restrict__ o1,
    unsigned short* __restrict__ o2, unsigned short* __restrict__ o3)
{
    __shared__ float t[32][33];
    const int bx = blockIdx.x;
    if (bx < 12288) {
        const int i = bx * 256 + threadIdx.x;   // float4 index
        const bool second = (i >= 1572864);
        const int idx = second ? i - 1572864 : i;
        const float4 v = second ? ((const float4*)enc)[idx] : ((const float4*)x)[idx];
        ushort4 o;
        o.x = f2bf(v.x); o.y = f2bf(v.y); o.z = f2bf(v.z); o.w = f2bf(v.w);
        if (second) ((ushort4*)eb)[idx] = o;
        else        ((ushort4*)xb)[idx] = o;
        return;
    }
    const int z  = bx - 12288;                  // 0..2303
    const int wi = z / 576;                     // which weight
    const int tt = z % 576;                     // 24x24 tiles
    const float* w; unsigned short* o;
    switch (wi) {
        case 0:  w = w0; o = o0; break;
        case 1:  w = w1; o = o1; break;
        case 2:  w = w2; o = o2; break;
        default: w = w3; o = o3; break;
    }
    const int tx = threadIdx.x & 31;
    const int ty = threadIdx.x >> 5;            // 0..7
    const int k0 = (tt % 24) * 32;
    const int n0 = (tt / 24) * 32;
#pragma unroll
    for (int i = 0; i < 4; ++i)
        t[ty + i * 8][tx] = w[(long)(k0 + ty + i * 8) * 768 + n0 + tx];
    __syncthreads();
#pragma unroll
    for (int i = 0; i < 4; ++i)
        o[(long)(n0 + ty + i * 8) * 768 + k0 + tx] = f2bf(t[tx][ty + i * 8]);
}

__global__ __launch_bounds__(256) void softmax_rows(
    const float* __restrict__ S, unsigned short* __restrict__ P)
{
    const long row = blockIdx.x;                 // 8192 rows of 1024
    const float* s = S + row * 1024;
    unsigned short* p = P + row * 1024;
    const int tid  = threadIdx.x;
    const int lane = tid & 63;
    const int wave = tid >> 6;

    float4 v = ((const float4*)s)[tid];
    float m = fmaxf(fmaxf(v.x, v.y), fmaxf(v.z, v.w));
#pragma unroll
    for (int off = 32; off > 0; off >>= 1)
        m = fmaxf(m, __shfl_xor(m, off));
    __shared__ float redm[4], reds[4];
    if (lane == 0) redm[wave] = m;
    __syncthreads();
    m = fmaxf(fmaxf(redm[0], redm[1]), fmaxf(redm[2], redm[3]));

    const float e0 = __expf(v.x - m), e1 = __expf(v.y - m);
    const float e2 = __expf(v.z - m), e3 = __expf(v.w - m);
    float sum = e0 + e1 + e2 + e3;
#pragma unroll
    for (int off = 32; off > 0; off >>= 1)
        sum += __shfl_xor(sum, off);
    if (lane == 0) reds[wave] = sum;
    __syncthreads();
    const float inv = 1.0f / (reds[0] + reds[1] + reds[2] + reds[3]);

    ushort4 o;
    o.x = f2bf(e0 * inv); o.y = f2bf(e1 * inv);
    o.z = f2bf(e2 * inv); o.w = f2bf(e3 * inv);
    ((ushort4*)p)[tid] = o;
}

// ---------------------------------------------------------------------------

extern "C" void kernel_launch(void* const* d_in, const int* in_sizes, int n_in,
                              void* d_out, int out_size, void* d_ws, size_t ws_size,
                              hipStream_t stream) {
    const float* x   = (const float*)d_in[0];
    const float* enc = (const float*)d_in[1];
    const float* Wq  = (const float*)d_in[2];
    const float* bq  = (const float*)d_in[3];
    const float* Wk  = (const float*)d_in[4];
    const float* bk  = (const float*)d_in[5];
    const float* Wv  = (const float*)d_in[6];
    const float* bv  = (const float*)d_in[7];
    const float* Wp  = (const float*)d_in[8];
    const float* bp  = (const float*)d_in[9];
    float* out = (float*)d_out;

    // workspace layout (bytes); peak need ~101.2 MB
    char* ws = (char*)d_ws;
    unsigned short* xb  = (unsigned short*)(ws + 0);         // 12582912
    unsigned short* eb  = (unsigned short*)(ws + 12582912);  // 12582912
    unsigned short* q   = (unsigned short*)(ws + 25165824);  // 12582912
    unsigned short* k   = (unsigned short*)(ws + 37748736);  // 12582912
    unsigned short* vt  = (unsigned short*)(ws + 50331648);  // 12582912 [B][H][S]
    unsigned short* wqt = (unsigned short*)(ws + 62914560);  // 1179648
    unsigned short* wkt = (unsigned short*)(ws + 64094208);  // 1179648
    unsigned short* wvt = (unsigned short*)(ws + 65273856);  // 1179648
    unsigned short* wpt = (unsigned short*)(ws + 66453504);  // 1179648
    float*          sc  = (float*)(ws + 67633152);           // 33554432 fp32 scores
    unsigned short* p   = (unsigned short*)(ws + 0);         // 16777216, overlays xb/eb (dead)
    unsigned short* ao  = (unsigned short*)(ws + 67633152);  // 12582912, overlays sc (dead)

    const float scale = 0.03608439182435161f;  // 1/sqrt(768)

    // 1. prep: fp32->bf16 inputs + W^T bf16 (fused)
    prep<<<14592, 256, 0, stream>>>(x, enc, xb, eb, Wq, Wk, Wv, Wp,
                                    wqt, wkt, wvt, wpt);

    // 2. q/k/v projections: 256x128 tiles, XCD-grouped flat grid
    proj_qkv<<<dim3(192, 1, 3), 512, 0, stream>>>(xb, eb, wqt, wkt, wvt,
                                                  bq, bk, bv, q, k, vt);

    // 3. scores = q k^T * scale (fp32), one batch per XCD
    scores_gemm<<<dim3(512, 1, 1), 256, 0, stream>>>(q, k, sc, scale);

    // 4. softmax rows -> bf16 P
    softmax_rows<<<8192, 256, 0, stream>>>(sc, p);

    // 5. ao = P @ V, one batch per XCD
    pv_gemm<<<dim3(384, 1, 1), 256, 0, stream>>>(p, vt, ao);

    // 6. out = ao @ Wp + bp (256x128 tiles)
    outproj_gemm<<<dim3(192, 1, 1), 512, 0, stream>>>(ao, wpt, out, bp);
}

// Round 9
// 214.682 us; speedup vs baseline: 1.1118x; 1.1118x over previous
//
#include <hip/hip_runtime.h>

// ---------------------------------------------------------------------------
// CrossAttention: B=8, T=S=1024, E=H=768, fp32 in/out, bf16 MFMA internally.
//
// Round 18: grid-balance round. r13 core is champion (55.8us proj); R16/R17
// schedule/intensity probes both lost. Remaining counter-supported theory:
// grid quantization at 2 blocks/CU (512 resident):
//   proj 1152 blocks = 2.25 rounds (ragged tail), pv/outproj 384 = 0.75
//   round (half the CUs carry 2 blocks, half 1 -> 33% imbalance).
// Fix: templated column width NB in {128,96}. 128x96 tiles give
//   proj 3x512 (3.0 even rounds), pv 512 (1.0), outproj 512 (1.0);
//   scores stays 128x128 at 512 (already perfect).
// Core schedule byte-identical (BK=64 counted-vmcnt dbuf, 2 blk/CU);
// NB=96 stages 4 A + 3 B insts -> vmcnt(7); LDS 56KB. Staging row map
// unified to row=i*32+(tid>>3): same swizzle algebra (i*32 === 0 mod 8),
// same wave-uniform-base + lane*16 LDS pattern (required by global_load_lds).
// ---------------------------------------------------------------------------

typedef __bf16 bf16x8 __attribute__((ext_vector_type(8)));
typedef float  f32x4  __attribute__((ext_vector_type(4)));

#define WAIT_VM8 __builtin_amdgcn_s_waitcnt(0x0F78)   // vmcnt(8), lgkm/exp nowait
#define WAIT_VM7 __builtin_amdgcn_s_waitcnt(0x0F77)   // vmcnt(7)
#define WAIT_VM0 __builtin_amdgcn_s_waitcnt(0x0F70)   // vmcnt(0)
#define BAR      __builtin_amdgcn_s_barrier()

__device__ __forceinline__ unsigned short f2bf(float f) {
    unsigned int u = __float_as_uint(f);
    u += 0x7fffu + ((u >> 16) & 1u);   // RNE; inputs are finite
    return (unsigned short)(u >> 16);
}

__device__ __forceinline__ void async_copy16(const void* g, void* s) {
    __builtin_amdgcn_global_load_lds(
        (const __attribute__((address_space(1))) void*)g,
        (__attribute__((address_space(3))) void*)s, 16, 0, 0);
}

// Block computes C[row0:row0+128, col0:col0+NB], NB in {96,128}.
// Ag = A + row0*K ([*,K] bf16 row-major); Bg = B^T + col0*K ([*,K]).
// Exactly one of Cf/Cb non-null. transC: store C^T as [b][H][S] (vt).
template<int NB>
__device__ __forceinline__ void gemm_core(
    const unsigned short* __restrict__ Ag,
    const unsigned short* __restrict__ Bg,
    const int K,
    float* __restrict__ Cf, unsigned short* __restrict__ Cb,
    const long ldc, const int transC, const float* __restrict__ bias,
    const float scale, const long row0, const long col0)
{
    constexpr int NJ  = NB / 32;          // B col-frags per wave-half: 3 or 4
    constexpr int NBH = NB / 32;          // B staging insts: 3 or 4

    __shared__ __align__(16) unsigned short As0[8192];       // [128][64] swizzled
    __shared__ __align__(16) unsigned short As1[8192];
    __shared__ __align__(16) unsigned short Bs0[NB * 64];    // [NB][64] swizzled
    __shared__ __align__(16) unsigned short Bs1[NB * 64];

    const int tid  = threadIdx.x;
    const int lane = tid & 63;
    const int quad = lane >> 4;
    const int l16  = lane & 15;
    const int wv   = tid >> 6;
    const int wm   = (wv >> 1) * 64;
    const int wn   = (wv & 1) * (NB / 2);

    // staging: inst i covers row r = i*32 + (tid>>3), linear slot s = tid&7;
    // source k-chunk j = s ^ (r&7) = (tid&7)^((tid>>3)&7)  (i*32 === 0 mod 8).
    // LDS dst elem = r*64 + s*8 = i*2048 + tid*8  (wave-uniform base + lane*16B).
    const int j8 = ((tid & 7) ^ ((tid >> 3) & 7)) * 8;     // src k-offset, elems
    const unsigned short* a_src = Ag + (long)(tid >> 3) * K + j8;
    const unsigned short* b_src = Bg + (long)(tid >> 3) * K + j8;
    const int dofs = tid * 8;

    f32x4 acc[4][NJ];
#pragma unroll
    for (int i = 0; i < 4; ++i)
#pragma unroll
        for (int j = 0; j < NJ; ++j)
            acc[i][j] = f32x4{0.f, 0.f, 0.f, 0.f};

    // one tile = 4 A + NBH B DMA instructions per thread
    auto stage = [&](unsigned short* dA, unsigned short* dB, int k0) {
#pragma unroll
        for (int i = 0; i < 4; ++i)
            async_copy16(a_src + (long)(i * 32) * K + k0, &dA[i * 2048 + dofs]);
#pragma unroll
        for (int i = 0; i < NBH; ++i)
            async_copy16(b_src + (long)(i * 32) * K + k0, &dB[i * 2048 + dofs]);
    };

    // 4*NJ*2 MFMA per wave per tile (two k-halves of 32)
    auto compute = [&](const unsigned short* sA, const unsigned short* sB) {
#pragma unroll
        for (int h = 0; h < 2; ++h) {
            bf16x8 af[4], bf[NJ];
            const int sl = ((quad + h * 4) ^ (l16 & 7)) * 8;
#pragma unroll
            for (int i = 0; i < 4; ++i)
                af[i] = *(const bf16x8*)&sA[(wm + i * 16 + l16) * 64 + sl];
#pragma unroll
            for (int j = 0; j < NJ; ++j)
                bf[j] = *(const bf16x8*)&sB[(wn + j * 16 + l16) * 64 + sl];
#pragma unroll
            for (int i = 0; i < 4; ++i)
#pragma unroll
                for (int j = 0; j < NJ; ++j)
                    acc[i][j] = __builtin_amdgcn_mfma_f32_16x16x32_bf16(
                        af[i], bf[j], acc[i][j], 0, 0, 0);
        }
    };

    const int nk = K >> 6;            // 12 or 16: even, >= 4
    stage(As0, Bs0, 0);               // tile 0 -> buf0
    stage(As1, Bs1, 64);              // tile 1 -> buf1
    int k0 = 128;

    for (int t = 0; t < nk - 2; t += 2) {
        if constexpr (NB == 128) { WAIT_VM8; } else { WAIT_VM7; }
        BAR;                          // buf0 (tile t) landed everywhere
        compute(As0, Bs0);
        BAR;                          // all waves done reading buf0
        stage(As0, Bs0, k0); k0 += 64;

        if constexpr (NB == 128) { WAIT_VM8; } else { WAIT_VM7; }
        BAR;                          // buf1 (tile t+1) landed
        compute(As1, Bs1);
        BAR;
        stage(As1, Bs1, k0); k0 += 64;
    }
    if constexpr (NB == 128) { WAIT_VM8; } else { WAIT_VM7; }
    BAR;                              // tile nk-2
    compute(As0, Bs0);
    WAIT_VM0; BAR;                    // tile nk-1
    compute(As1, Bs1);

    // epilogue: C/D layout col=lane&15, row=quad*4+reg  [m89/m91 verified]
#pragma unroll
    for (int i = 0; i < 4; ++i) {
#pragma unroll
        for (int j = 0; j < NJ; ++j) {
            const long r0 = row0 + wm + i * 16 + quad * 4;
            const long c  = col0 + wn + j * 16 + l16;
            const float bb = bias ? bias[c] : 0.0f;
#pragma unroll
            for (int r = 0; r < 4; ++r) {
                const float v = acc[i][j][r] * scale + bb;
                const long rr = r0 + r;
                if (Cb) {
                    if (transC) {
                        Cb[((rr >> 10) * 768 + c) * 1024 + (rr & 1023)] = f2bf(v);
                    } else {
                        Cb[rr * ldc + c] = f2bf(v);
                    }
                } else {
                    Cf[rr * ldc + c] = v;
                }
            }
        }
    }
}

// ---------------------------------------------------------------------------
// XCD-locality mapping (HW round-robins consecutive blockIdx.x over 8 XCDs).

__global__ __launch_bounds__(256, 2) void proj_qkv(
    const unsigned short* __restrict__ xb, const unsigned short* __restrict__ eb,
    const unsigned short* __restrict__ wqt, const unsigned short* __restrict__ wkt,
    const unsigned short* __restrict__ wvt,
    const float* __restrict__ bq, const float* __restrict__ bk,
    const float* __restrict__ bv,
    unsigned short* __restrict__ q, unsigned short* __restrict__ k,
    unsigned short* __restrict__ vt)
{
    const unsigned short *A, *Bt; const float* bias; unsigned short* C;
    int trans = 0;
    switch (blockIdx.z) {
        case 0:  A = xb; Bt = wqt; bias = bq; C = q;  break;
        case 1:  A = eb; Bt = wkt; bias = bk; C = k;  break;
        default: A = eb; Bt = wvt; bias = bv; C = vt; trans = 1; break;
    }
    // p in [0,512): xcd g owns rows g*8..g*8+7 x all 8 col-tiles of 96.
    const int p = blockIdx.x;
    const int g = p & 7, m = p >> 3;          // m in [0,64)
    const long row0 = (long)(g * 8 + (m & 7)) * 128;
    const long col0 = (long)(m >> 3) * 96;
    gemm_core<96>(A + row0 * 768, Bt + col0 * 768, 768,
                  nullptr, C, 768, trans, bias, 1.0f, row0, col0);
}

__global__ __launch_bounds__(256, 2) void scores_gemm(
    const unsigned short* __restrict__ q, const unsigned short* __restrict__ k,
    float* __restrict__ sc, float scale)
{
    const int p = blockIdx.x;                 // [0,512): batch pinned to XCD
    const long b = p & 7;
    const int m  = p >> 3;                    // [0,64)
    const long row0 = (long)(m & 7) * 128;
    const long col0 = (long)(m >> 3) * 128;
    gemm_core<128>(q + (b * 1024 + row0) * 768, k + b * 786432 + col0 * 768, 768,
                   sc + b * 1048576, nullptr, 1024, 0, nullptr, scale, row0, col0);
}

__global__ __launch_bounds__(256, 2) void pv_gemm(
    const unsigned short* __restrict__ p_, const unsigned short* __restrict__ vt,
    unsigned short* __restrict__ ao)
{
    const int p = blockIdx.x;                 // [0,512): batch pinned to XCD
    const long b = p & 7;
    const int m  = p >> 3;                    // [0,64)
    const long row0 = (long)(m & 7) * 128;
    const long col0 = (long)(m >> 3) * 96;    // 8 col-tiles of 96 = 768
    gemm_core<96>(p_ + (b * 1024 + row0) * 1024, vt + b * 786432 + col0 * 1024, 1024,
                  nullptr, ao + b * 786432, 768, 0, nullptr, 1.0f, row0, col0);
}

__global__ __launch_bounds__(256, 2) void outproj_gemm(
    const unsigned short* __restrict__ ao, const unsigned short* __restrict__ wpt,
    float* __restrict__ out, const float* __restrict__ bp)
{
    const int p = blockIdx.x;                 // [0,512)
    const int g = p & 7, m = p >> 3;          // m in [0,64)
    const long row0 = (long)(g * 8 + (m & 7)) * 128;
    const long col0 = (long)(m >> 3) * 96;
    gemm_core<96>(ao + row0 * 768, wpt + col0 * 768, 768,
                  out, nullptr, 768, 0, bp, 1.0f, row0, col0);
}

// ---------------------------------------------------------------------------
// prep: fp32->bf16 conversion of x/enc (blocks 0..12287) + 32x32 bf16
// transposes of the four weights (blocks 12288..14591).

__global__ __launch_bounds__(256) void prep(
    const float* __restrict__ x, const float* __restrict__ enc,
    unsigned short* __restrict__ xb, unsigned short* __restrict__ eb,
    const float* __restrict__ w0, const float* __restrict__ w1,
    const float* __restrict__ w2, const float* __restrict__ w3,
    unsigned short* __restrict__ o0, unsigned short* __restrict__ o1,
    unsigned short* __restrict__ o2, unsigned short* __restrict__ o3)
{
    __shared__ float t[32][33];
    const int bx = blockIdx.x;
    if (bx < 12288) {
        const int i = bx * 256 + threadIdx.x;   // float4 index
        const bool second = (i >= 1572864);
        const int idx = second ? i - 1572864 : i;
        const float4 v = second ? ((const float4*)enc)[idx] : ((const float4*)x)[idx];
        ushort4 o;
        o.x = f2bf(v.x); o.y = f2bf(v.y); o.z = f2bf(v.z); o.w = f2bf(v.w);
        if (second) ((ushort4*)eb)[idx] = o;
        else        ((ushort4*)xb)[idx] = o;
        return;
    }
    const int z  = bx - 12288;                  // 0..2303
    const int wi = z / 576;                     // which weight
    const int tt = z % 576;                     // 24x24 tiles
    const float* w; unsigned short* o;
    switch (wi) {
        case 0:  w = w0; o = o0; break;
        case 1:  w = w1; o = o1; break;
        case 2:  w = w2; o = o2; break;
        default: w = w3; o = o3; break;
    }
    const int tx = threadIdx.x & 31;
    const int ty = threadIdx.x >> 5;            // 0..7
    const int k0 = (tt % 24) * 32;
    const int n0 = (tt / 24) * 32;
#pragma unroll
    for (int i = 0; i < 4; ++i)
        t[ty + i * 8][tx] = w[(long)(k0 + ty + i * 8) * 768 + n0 + tx];
    __syncthreads();
#pragma unroll
    for (int i = 0; i < 4; ++i)
        o[(long)(n0 + ty + i * 8) * 768 + k0 + tx] = f2bf(t[tx][ty + i * 8]);
}

__global__ __launch_bounds__(256) void softmax_rows(
    const float* __restrict__ S, unsigned short* __restrict__ P)
{
    const long row = blockIdx.x;                 // 8192 rows of 1024
    const float* s = S + row * 1024;
    unsigned short* p = P + row * 1024;
    const int tid  = threadIdx.x;
    const int lane = tid & 63;
    const int wave = tid >> 6;

    float4 v = ((const float4*)s)[tid];
    float m = fmaxf(fmaxf(v.x, v.y), fmaxf(v.z, v.w));
#pragma unroll
    for (int off = 32; off > 0; off >>= 1)
        m = fmaxf(m, __shfl_xor(m, off));
    __shared__ float redm[4], reds[4];
    if (lane == 0) redm[wave] = m;
    __syncthreads();
    m = fmaxf(fmaxf(redm[0], redm[1]), fmaxf(redm[2], redm[3]));

    const float e0 = __expf(v.x - m), e1 = __expf(v.y - m);
    const float e2 = __expf(v.z - m), e3 = __expf(v.w - m);
    float sum = e0 + e1 + e2 + e3;
#pragma unroll
    for (int off = 32; off > 0; off >>= 1)
        sum += __shfl_xor(sum, off);
    if (lane == 0) reds[wave] = sum;
    __syncthreads();
    const float inv = 1.0f / (reds[0] + reds[1] + reds[2] + reds[3]);

    ushort4 o;
    o.x = f2bf(e0 * inv); o.y = f2bf(e1 * inv);
    o.z = f2bf(e2 * inv); o.w = f2bf(e3 * inv);
    ((ushort4*)p)[tid] = o;
}

// ---------------------------------------------------------------------------

extern "C" void kernel_launch(void* const* d_in, const int* in_sizes, int n_in,
                              void* d_out, int out_size, void* d_ws, size_t ws_size,
                              hipStream_t stream) {
    const float* x   = (const float*)d_in[0];
    const float* enc = (const float*)d_in[1];
    const float* Wq  = (const float*)d_in[2];
    const float* bq  = (const float*)d_in[3];
    const float* Wk  = (const float*)d_in[4];
    const float* bk  = (const float*)d_in[5];
    const float* Wv  = (const float*)d_in[6];
    const float* bv  = (const float*)d_in[7];
    const float* Wp  = (const float*)d_in[8];
    const float* bp  = (const float*)d_in[9];
    float* out = (float*)d_out;

    // workspace layout (bytes); peak need ~101.2 MB
    char* ws = (char*)d_ws;
    unsigned short* xb  = (unsigned short*)(ws + 0);         // 12582912
    unsigned short* eb  = (unsigned short*)(ws + 12582912);  // 12582912
    unsigned short* q   = (unsigned short*)(ws + 25165824);  // 12582912
    unsigned short* k   = (unsigned short*)(ws + 37748736);  // 12582912
    unsigned short* vt  = (unsigned short*)(ws + 50331648);  // 12582912 [B][H][S]
    unsigned short* wqt = (unsigned short*)(ws + 62914560);  // 1179648
    unsigned short* wkt = (unsigned short*)(ws + 64094208);  // 1179648
    unsigned short* wvt = (unsigned short*)(ws + 65273856);  // 1179648
    unsigned short* wpt = (unsigned short*)(ws + 66453504);  // 1179648
    float*          sc  = (float*)(ws + 67633152);           // 33554432 fp32 scores
    unsigned short* p   = (unsigned short*)(ws + 0);         // 16777216, overlays xb/eb (dead)
    unsigned short* ao  = (unsigned short*)(ws + 67633152);  // 12582912, overlays sc (dead)

    const float scale = 0.03608439182435161f;  // 1/sqrt(768)

    // 1. prep: fp32->bf16 inputs + W^T bf16 (fused)
    prep<<<14592, 256, 0, stream>>>(x, enc, xb, eb, Wq, Wk, Wv, Wp,
                                    wqt, wkt, wvt, wpt);

    // 2. q/k/v projections: 128x96 tiles, 512 blocks/z = 3.0 even rounds
    proj_qkv<<<dim3(512, 1, 3), 256, 0, stream>>>(xb, eb, wqt, wkt, wvt,
                                                  bq, bk, bv, q, k, vt);

    // 3. scores = q k^T * scale (fp32): 128x128, 512 blocks (1.0 round)
    scores_gemm<<<dim3(512, 1, 1), 256, 0, stream>>>(q, k, sc, scale);

    // 4. softmax rows -> bf16 P
    softmax_rows<<<8192, 256, 0, stream>>>(sc, p);

    // 5. ao = P @ V: 128x96, 512 blocks (1.0 round)
    pv_gemm<<<dim3(512, 1, 1), 256, 0, stream>>>(p, vt, ao);

    // 6. out = ao @ Wp + bp: 128x96, 512 blocks (1.0 round)
    outproj_gemm<<<dim3(512, 1, 1), 256, 0, stream>>>(ao, wpt, out, bp);
}

// Round 10
// 212.846 us; speedup vs baseline: 1.1214x; 1.0086x over previous
//
#include <hip/hip_runtime.h>

// ---------------------------------------------------------------------------
// CrossAttention: B=8, T=S=1024, E=H=768, fp32 in/out, bf16 MFMA internally.
//
// Round 19: staged-byte reduction. r18 (grid-balanced 128x96, champion
// 214.7us) is ingest-bound at ~16 B/cy/CU (~ceiling for short-K). The k and
// v projections stage the SAME A (eb) twice -> fuse into one proj_kv kernel:
// per block stage A once + two B panels (wkt,wvt), two acc sets, two
// epilogues (k normal, vt transposed). Staged bytes for the kv pair:
// 686KB -> 490KB (-29%). Separate kernel (LDS = union of statics):
// 80KB = 2x(16K A + 12K Bk + 12K Bv) -> exactly 2 blocks/CU.
// stage = 10 DMA insts -> counted vmcnt(10); same r9/r18 sync discipline,
// DMA-only LDS writes. proj_q (xb@wqt) keeps the verified r18 core.
// Grids: proj_q 512, proj_kv 512 -> 1.0 even round each (r18's lesson).
// Everything else byte-identical to r18.
// ---------------------------------------------------------------------------

typedef __bf16 bf16x8 __attribute__((ext_vector_type(8)));
typedef float  f32x4  __attribute__((ext_vector_type(4)));

#define WAIT_VM8  __builtin_amdgcn_s_waitcnt(0x0F78)   // vmcnt(8), lgkm/exp nowait
#define WAIT_VM7  __builtin_amdgcn_s_waitcnt(0x0F77)   // vmcnt(7)
#define WAIT_VM10 __builtin_amdgcn_s_waitcnt(0x0F7A)   // vmcnt(10)
#define WAIT_VM0  __builtin_amdgcn_s_waitcnt(0x0F70)   // vmcnt(0)
#define BAR       __builtin_amdgcn_s_barrier()

__device__ __forceinline__ unsigned short f2bf(float f) {
    unsigned int u = __float_as_uint(f);
    u += 0x7fffu + ((u >> 16) & 1u);   // RNE; inputs are finite
    return (unsigned short)(u >> 16);
}

__device__ __forceinline__ void async_copy16(const void* g, void* s) {
    __builtin_amdgcn_global_load_lds(
        (const __attribute__((address_space(1))) void*)g,
        (__attribute__((address_space(3))) void*)s, 16, 0, 0);
}

// Block computes C[row0:row0+128, col0:col0+NB], NB in {96,128}.
// Ag = A + row0*K ([*,K] bf16 row-major); Bg = B^T + col0*K ([*,K]).
// Exactly one of Cf/Cb non-null. transC: store C^T as [b][H][S] (vt).
template<int NB>
__device__ __forceinline__ void gemm_core(
    const unsigned short* __restrict__ Ag,
    const unsigned short* __restrict__ Bg,
    const int K,
    float* __restrict__ Cf, unsigned short* __restrict__ Cb,
    const long ldc, const int transC, const float* __restrict__ bias,
    const float scale, const long row0, const long col0)
{
    constexpr int NJ  = NB / 32;          // B col-frags per wave-half: 3 or 4
    constexpr int NBH = NB / 32;          // B staging insts: 3 or 4

    __shared__ __align__(16) unsigned short As0[8192];       // [128][64] swizzled
    __shared__ __align__(16) unsigned short As1[8192];
    __shared__ __align__(16) unsigned short Bs0[NB * 64];    // [NB][64] swizzled
    __shared__ __align__(16) unsigned short Bs1[NB * 64];

    const int tid  = threadIdx.x;
    const int lane = tid & 63;
    const int quad = lane >> 4;
    const int l16  = lane & 15;
    const int wv   = tid >> 6;
    const int wm   = (wv >> 1) * 64;
    const int wn   = (wv & 1) * (NB / 2);

    // staging: inst i covers row r = i*32 + (tid>>3), linear slot s = tid&7;
    // source k-chunk j = s ^ (r&7) = (tid&7)^((tid>>3)&7)  (i*32 === 0 mod 8).
    // LDS dst elem = r*64 + s*8 = i*2048 + tid*8  (wave-uniform base + lane*16B).
    const int j8 = ((tid & 7) ^ ((tid >> 3) & 7)) * 8;     // src k-offset, elems
    const unsigned short* a_src = Ag + (long)(tid >> 3) * K + j8;
    const unsigned short* b_src = Bg + (long)(tid >> 3) * K + j8;
    const int dofs = tid * 8;

    f32x4 acc[4][NJ];
#pragma unroll
    for (int i = 0; i < 4; ++i)
#pragma unroll
        for (int j = 0; j < NJ; ++j)
            acc[i][j] = f32x4{0.f, 0.f, 0.f, 0.f};

    // one tile = 4 A + NBH B DMA instructions per thread
    auto stage = [&](unsigned short* dA, unsigned short* dB, int k0) {
#pragma unroll
        for (int i = 0; i < 4; ++i)
            async_copy16(a_src + (long)(i * 32) * K + k0, &dA[i * 2048 + dofs]);
#pragma unroll
        for (int i = 0; i < NBH; ++i)
            async_copy16(b_src + (long)(i * 32) * K + k0, &dB[i * 2048 + dofs]);
    };

    // 4*NJ*2 MFMA per wave per tile (two k-halves of 32)
    auto compute = [&](const unsigned short* sA, const unsigned short* sB) {
#pragma unroll
        for (int h = 0; h < 2; ++h) {
            bf16x8 af[4], bf[NJ];
            const int sl = ((quad + h * 4) ^ (l16 & 7)) * 8;
#pragma unroll
            for (int i = 0; i < 4; ++i)
                af[i] = *(const bf16x8*)&sA[(wm + i * 16 + l16) * 64 + sl];
#pragma unroll
            for (int j = 0; j < NJ; ++j)
                bf[j] = *(const bf16x8*)&sB[(wn + j * 16 + l16) * 64 + sl];
#pragma unroll
            for (int i = 0; i < 4; ++i)
#pragma unroll
                for (int j = 0; j < NJ; ++j)
                    acc[i][j] = __builtin_amdgcn_mfma_f32_16x16x32_bf16(
                        af[i], bf[j], acc[i][j], 0, 0, 0);
        }
    };

    const int nk = K >> 6;            // 12 or 16: even, >= 4
    stage(As0, Bs0, 0);               // tile 0 -> buf0
    stage(As1, Bs1, 64);              // tile 1 -> buf1
    int k0 = 128;

    for (int t = 0; t < nk - 2; t += 2) {
        if constexpr (NB == 128) { WAIT_VM8; } else { WAIT_VM7; }
        BAR;                          // buf0 (tile t) landed everywhere
        compute(As0, Bs0);
        BAR;                          // all waves done reading buf0
        stage(As0, Bs0, k0); k0 += 64;

        if constexpr (NB == 128) { WAIT_VM8; } else { WAIT_VM7; }
        BAR;                          // buf1 (tile t+1) landed
        compute(As1, Bs1);
        BAR;
        stage(As1, Bs1, k0); k0 += 64;
    }
    if constexpr (NB == 128) { WAIT_VM8; } else { WAIT_VM7; }
    BAR;                              // tile nk-2
    compute(As0, Bs0);
    WAIT_VM0; BAR;                    // tile nk-1
    compute(As1, Bs1);

    // epilogue: C/D layout col=lane&15, row=quad*4+reg  [m89/m91 verified]
#pragma unroll
    for (int i = 0; i < 4; ++i) {
#pragma unroll
        for (int j = 0; j < NJ; ++j) {
            const long r0 = row0 + wm + i * 16 + quad * 4;
            const long c  = col0 + wn + j * 16 + l16;
            const float bb = bias ? bias[c] : 0.0f;
#pragma unroll
            for (int r = 0; r < 4; ++r) {
                const float v = acc[i][j][r] * scale + bb;
                const long rr = r0 + r;
                if (Cb) {
                    if (transC) {
                        Cb[((rr >> 10) * 768 + c) * 1024 + (rr & 1023)] = f2bf(v);
                    } else {
                        Cb[rr * ldc + c] = f2bf(v);
                    }
                } else {
                    Cf[rr * ldc + c] = v;
                }
            }
        }
    }
}

// ---------------------------------------------------------------------------
// Dual-B core for the k/v projections: stages A (eb strip) ONCE, two B panels
// (wkt, wvt), two accumulator sets. NB=96, K=768. LDS 80KB -> 2 blocks/CU.
__device__ __forceinline__ void gemm_core_kv(
    const unsigned short* __restrict__ Ag,    // eb + row0*768
    const unsigned short* __restrict__ Bk,    // wkt + col0*768
    const unsigned short* __restrict__ Bv,    // wvt + col0*768
    const float* __restrict__ bk, const float* __restrict__ bv,
    unsigned short* __restrict__ kout,        // [8192][768] bf16
    unsigned short* __restrict__ vtout,       // [8][768][1024] bf16
    const long row0, const long col0)
{
    constexpr int K = 768;

    __shared__ __align__(16) unsigned short As0[8192];   // [128][64] swizzled
    __shared__ __align__(16) unsigned short As1[8192];
    __shared__ __align__(16) unsigned short Bk0[6144];   // [96][64] swizzled
    __shared__ __align__(16) unsigned short Bk1[6144];
    __shared__ __align__(16) unsigned short Bv0[6144];
    __shared__ __align__(16) unsigned short Bv1[6144];

    const int tid  = threadIdx.x;
    const int lane = tid & 63;
    const int quad = lane >> 4;
    const int l16  = lane & 15;
    const int wv   = tid >> 6;
    const int wm   = (wv >> 1) * 64;
    const int wn   = (wv & 1) * 48;

    const int j8 = ((tid & 7) ^ ((tid >> 3) & 7)) * 8;     // src k-offset, elems
    const unsigned short* a_src  = Ag + (long)(tid >> 3) * K + j8;
    const unsigned short* bk_src = Bk + (long)(tid >> 3) * K + j8;
    const unsigned short* bv_src = Bv + (long)(tid >> 3) * K + j8;
    const int dofs = tid * 8;

    f32x4 acck[4][3], accv[4][3];
#pragma unroll
    for (int i = 0; i < 4; ++i)
#pragma unroll
        for (int j = 0; j < 3; ++j) {
            acck[i][j] = f32x4{0.f, 0.f, 0.f, 0.f};
            accv[i][j] = f32x4{0.f, 0.f, 0.f, 0.f};
        }

    // one tile = 4 A + 3 Bk + 3 Bv = 10 DMA instructions per thread
    auto stage = [&](unsigned short* dA, unsigned short* dK, unsigned short* dV,
                     int k0) {
#pragma unroll
        for (int i = 0; i < 4; ++i)
            async_copy16(a_src + (long)(i * 32) * K + k0, &dA[i * 2048 + dofs]);
#pragma unroll
        for (int i = 0; i < 3; ++i)
            async_copy16(bk_src + (long)(i * 32) * K + k0, &dK[i * 2048 + dofs]);
#pragma unroll
        for (int i = 0; i < 3; ++i)
            async_copy16(bv_src + (long)(i * 32) * K + k0, &dV[i * 2048 + dofs]);
    };

    // 48 MFMA per wave per tile (two k-halves x 4i x 3j x 2 outputs)
    auto compute = [&](const unsigned short* sA, const unsigned short* sK,
                       const unsigned short* sV) {
#pragma unroll
        for (int h = 0; h < 2; ++h) {
            bf16x8 af[4], bkf[3], bvf[3];
            const int sl = ((quad + h * 4) ^ (l16 & 7)) * 8;
#pragma unroll
            for (int i = 0; i < 4; ++i)
                af[i] = *(const bf16x8*)&sA[(wm + i * 16 + l16) * 64 + sl];
#pragma unroll
            for (int j = 0; j < 3; ++j) {
                bkf[j] = *(const bf16x8*)&sK[(wn + j * 16 + l16) * 64 + sl];
                bvf[j] = *(const bf16x8*)&sV[(wn + j * 16 + l16) * 64 + sl];
            }
#pragma unroll
            for (int i = 0; i < 4; ++i)
#pragma unroll
                for (int j = 0; j < 3; ++j) {
                    acck[i][j] = __builtin_amdgcn_mfma_f32_16x16x32_bf16(
                        af[i], bkf[j], acck[i][j], 0, 0, 0);
                    accv[i][j] = __builtin_amdgcn_mfma_f32_16x16x32_bf16(
                        af[i], bvf[j], accv[i][j], 0, 0, 0);
                }
        }
    };

    const int nk = K >> 6;            // 12
    stage(As0, Bk0, Bv0, 0);
    stage(As1, Bk1, Bv1, 64);
    int k0 = 128;

    for (int t = 0; t < nk - 2; t += 2) {
        WAIT_VM10; BAR;               // buf0 (tile t) landed; buf1's 10 in flight
        compute(As0, Bk0, Bv0);
        BAR;
        stage(As0, Bk0, Bv0, k0); k0 += 64;

        WAIT_VM10; BAR;
        compute(As1, Bk1, Bv1);
        BAR;
        stage(As1, Bk1, Bv1, k0); k0 += 64;
    }
    WAIT_VM10; BAR;
    compute(As0, Bk0, Bv0);
    WAIT_VM0; BAR;
    compute(As1, Bk1, Bv1);

    // epilogues: k (row-major) and vt (transposed [b][H][S])
#pragma unroll
    for (int i = 0; i < 4; ++i) {
#pragma unroll
        for (int j = 0; j < 3; ++j) {
            const long r0 = row0 + wm + i * 16 + quad * 4;
            const long c  = col0 + wn + j * 16 + l16;
            const float bbk = bk[c], bbv = bv[c];
#pragma unroll
            for (int r = 0; r < 4; ++r) {
                const long rr = r0 + r;
                kout[rr * 768 + c] = f2bf(acck[i][j][r] + bbk);
                vtout[((rr >> 10) * 768 + c) * 1024 + (rr & 1023)] =
                    f2bf(accv[i][j][r] + bbv);
            }
        }
    }
}

// ---------------------------------------------------------------------------
// XCD-locality mapping (HW round-robins consecutive blockIdx.x over 8 XCDs).

__global__ __launch_bounds__(256, 2) void proj_q(
    const unsigned short* __restrict__ xb, const unsigned short* __restrict__ wqt,
    const float* __restrict__ bq, unsigned short* __restrict__ q)
{
    const int p = blockIdx.x;                 // [0,512)
    const int g = p & 7, m = p >> 3;          // m in [0,64)
    const long row0 = (long)(g * 8 + (m & 7)) * 128;
    const long col0 = (long)(m >> 3) * 96;
    gemm_core<96>(xb + row0 * 768, wqt + col0 * 768, 768,
                  nullptr, q, 768, 0, bq, 1.0f, row0, col0);
}

__global__ __launch_bounds__(256, 2) void proj_kv(
    const unsigned short* __restrict__ eb,
    const unsigned short* __restrict__ wkt, const unsigned short* __restrict__ wvt,
    const float* __restrict__ bk, const float* __restrict__ bv,
    unsigned short* __restrict__ k, unsigned short* __restrict__ vt)
{
    const int p = blockIdx.x;                 // [0,512)
    const int g = p & 7, m = p >> 3;          // m in [0,64)
    const long row0 = (long)(g * 8 + (m & 7)) * 128;
    const long col0 = (long)(m >> 3) * 96;
    gemm_core_kv(eb + row0 * 768, wkt + col0 * 768, wvt + col0 * 768,
                 bk, bv, k, vt, row0, col0);
}

__global__ __launch_bounds__(256, 2) void scores_gemm(
    const unsigned short* __restrict__ q, const unsigned short* __restrict__ k,
    float* __restrict__ sc, float scale)
{
    const int p = blockIdx.x;                 // [0,512): batch pinned to XCD
    const long b = p & 7;
    const int m  = p >> 3;                    // [0,64)
    const long row0 = (long)(m & 7) * 128;
    const long col0 = (long)(m >> 3) * 128;
    gemm_core<128>(q + (b * 1024 + row0) * 768, k + b * 786432 + col0 * 768, 768,
                   sc + b * 1048576, nullptr, 1024, 0, nullptr, scale, row0, col0);
}

__global__ __launch_bounds__(256, 2) void pv_gemm(
    const unsigned short* __restrict__ p_, const unsigned short* __restrict__ vt,
    unsigned short* __restrict__ ao)
{
    const int p = blockIdx.x;                 // [0,512): batch pinned to XCD
    const long b = p & 7;
    const int m  = p >> 3;                    // [0,64)
    const long row0 = (long)(m & 7) * 128;
    const long col0 = (long)(m >> 3) * 96;    // 8 col-tiles of 96 = 768
    gemm_core<96>(p_ + (b * 1024 + row0) * 1024, vt + b * 786432 + col0 * 1024, 1024,
                  nullptr, ao + b * 786432, 768, 0, nullptr, 1.0f, row0, col0);
}

__global__ __launch_bounds__(256, 2) void outproj_gemm(
    const unsigned short* __restrict__ ao, const unsigned short* __restrict__ wpt,
    float* __restrict__ out, const float* __restrict__ bp)
{
    const int p = blockIdx.x;                 // [0,512)
    const int g = p & 7, m = p >> 3;          // m in [0,64)
    const long row0 = (long)(g * 8 + (m & 7)) * 128;
    const long col0 = (long)(m >> 3) * 96;
    gemm_core<96>(ao + row0 * 768, wpt + col0 * 768, 768,
                  out, nullptr, 768, 0, bp, 1.0f, row0, col0);
}

// ---------------------------------------------------------------------------
// prep: fp32->bf16 conversion of x/enc (blocks 0..12287) + 32x32 bf16
// transposes of the four weights (blocks 12288..14591).

__global__ __launch_bounds__(256) void prep(
    const float* __restrict__ x, const float* __restrict__ enc,
    unsigned short* __restrict__ xb, unsigned short* __restrict__ eb,
    const float* __restrict__ w0, const float* __restrict__ w1,
    const float* __restrict__ w2, const float* __restrict__ w3,
    unsigned short* __restrict__ o0, unsigned short* __restrict__ o1,
    unsigned short* __restrict__ o2, unsigned short* __restrict__ o3)
{
    __shared__ float t[32][33];
    const int bx = blockIdx.x;
    if (bx < 12288) {
        const int i = bx * 256 + threadIdx.x;   // float4 index
        const bool second = (i >= 1572864);
        const int idx = second ? i - 1572864 : i;
        const float4 v = second ? ((const float4*)enc)[idx] : ((const float4*)x)[idx];
        ushort4 o;
        o.x = f2bf(v.x); o.y = f2bf(v.y); o.z = f2bf(v.z); o.w = f2bf(v.w);
        if (second) ((ushort4*)eb)[idx] = o;
        else        ((ushort4*)xb)[idx] = o;
        return;
    }
    const int z  = bx - 12288;                  // 0..2303
    const int wi = z / 576;                     // which weight
    const int tt = z % 576;                     // 24x24 tiles
    const float* w; unsigned short* o;
    switch (wi) {
        case 0:  w = w0; o = o0; break;
        case 1:  w = w1; o = o1; break;
        case 2:  w = w2; o = o2; break;
        default: w = w3; o = o3; break;
    }
    const int tx = threadIdx.x & 31;
    const int ty = threadIdx.x >> 5;            // 0..7
    const int k0 = (tt % 24) * 32;
    const int n0 = (tt / 24) * 32;
#pragma unroll
    for (int i = 0; i < 4; ++i)
        t[ty + i * 8][tx] = w[(long)(k0 + ty + i * 8) * 768 + n0 + tx];
    __syncthreads();
#pragma unroll
    for (int i = 0; i < 4; ++i)
        o[(long)(n0 + ty + i * 8) * 768 + k0 + tx] = f2bf(t[tx][ty + i * 8]);
}

__global__ __launch_bounds__(256) void softmax_rows(
    const float* __restrict__ S, unsigned short* __restrict__ P)
{
    const long row = blockIdx.x;                 // 8192 rows of 1024
    const float* s = S + row * 1024;
    unsigned short* p = P + row * 1024;
    const int tid  = threadIdx.x;
    const int lane = tid & 63;
    const int wave = tid >> 6;

    float4 v = ((const float4*)s)[tid];
    float m = fmaxf(fmaxf(v.x, v.y), fmaxf(v.z, v.w));
#pragma unroll
    for (int off = 32; off > 0; off >>= 1)
        m = fmaxf(m, __shfl_xor(m, off));
    __shared__ float redm[4], reds[4];
    if (lane == 0) redm[wave] = m;
    __syncthreads();
    m = fmaxf(fmaxf(redm[0], redm[1]), fmaxf(redm[2], redm[3]));

    const float e0 = __expf(v.x - m), e1 = __expf(v.y - m);
    const float e2 = __expf(v.z - m), e3 = __expf(v.w - m);
    float sum = e0 + e1 + e2 + e3;
#pragma unroll
    for (int off = 32; off > 0; off >>= 1)
        sum += __shfl_xor(sum, off);
    if (lane == 0) reds[wave] = sum;
    __syncthreads();
    const float inv = 1.0f / (reds[0] + reds[1] + reds[2] + reds[3]);

    ushort4 o;
    o.x = f2bf(e0 * inv); o.y = f2bf(e1 * inv);
    o.z = f2bf(e2 * inv); o.w = f2bf(e3 * inv);
    ((ushort4*)p)[tid] = o;
}

// ---------------------------------------------------------------------------

extern "C" void kernel_launch(void* const* d_in, const int* in_sizes, int n_in,
                              void* d_out, int out_size, void* d_ws, size_t ws_size,
                              hipStream_t stream) {
    const float* x   = (const float*)d_in[0];
    const float* enc = (const float*)d_in[1];
    const float* Wq  = (const float*)d_in[2];
    const float* bq  = (const float*)d_in[3];
    const float* Wk  = (const float*)d_in[4];
    const float* bk  = (const float*)d_in[5];
    const float* Wv  = (const float*)d_in[6];
    const float* bv  = (const float*)d_in[7];
    const float* Wp  = (const float*)d_in[8];
    const float* bp  = (const float*)d_in[9];
    float* out = (float*)d_out;

    // workspace layout (bytes); peak need ~101.2 MB
    char* ws = (char*)d_ws;
    unsigned short* xb  = (unsigned short*)(ws + 0);         // 12582912
    unsigned short* eb  = (unsigned short*)(ws + 12582912);  // 12582912
    unsigned short* q   = (unsigned short*)(ws + 25165824);  // 12582912
    unsigned short* k   = (unsigned short*)(ws + 37748736);  // 12582912
    unsigned short* vt  = (unsigned short*)(ws + 50331648);  // 12582912 [B][H][S]
    unsigned short* wqt = (unsigned short*)(ws + 62914560);  // 1179648
    unsigned short* wkt = (unsigned short*)(ws + 64094208);  // 1179648
    unsigned short* wvt = (unsigned short*)(ws + 65273856);  // 1179648
    unsigned short* wpt = (unsigned short*)(ws + 66453504);  // 1179648
    float*          sc  = (float*)(ws + 67633152);           // 33554432 fp32 scores
    unsigned short* p   = (unsigned short*)(ws + 0);         // 16777216, overlays xb/eb (dead)
    unsigned short* ao  = (unsigned short*)(ws + 67633152);  // 12582912, overlays sc (dead)

    const float scale = 0.03608439182435161f;  // 1/sqrt(768)

    // 1. prep: fp32->bf16 inputs + W^T bf16 (fused)
    prep<<<14592, 256, 0, stream>>>(x, enc, xb, eb, Wq, Wk, Wv, Wp,
                                    wqt, wkt, wvt, wpt);

    // 2a. q projection: 128x96 tiles, 512 blocks (1.0 round)
    proj_q<<<512, 256, 0, stream>>>(xb, wqt, bq, q);

    // 2b. k+v projections fused (A staged once): 512 blocks (1.0 round)
    proj_kv<<<512, 256, 0, stream>>>(eb, wkt, wvt, bk, bv, k, vt);

    // 3. scores = q k^T * scale (fp32): 128x128, 512 blocks (1.0 round)
    scores_gemm<<<512, 256, 0, stream>>>(q, k, sc, scale);

    // 4. softmax rows -> bf16 P
    softmax_rows<<<8192, 256, 0, stream>>>(sc, p);

    // 5. ao = P @ V: 128x96, 512 blocks (1.0 round)
    pv_gemm<<<512, 256, 0, stream>>>(p, vt, ao);

    // 6. out = ao @ Wp + bp: 128x96, 512 blocks (1.0 round)
    outproj_gemm<<<512, 256, 0, stream>>>(ao, wpt, out, bp);
}

// Round 12
// 206.258 us; speedup vs baseline: 1.1572x; 1.0319x over previous
//
#include <hip/hip_runtime.h>

// ---------------------------------------------------------------------------
// CrossAttention: B=8, T=S=1024, E=H=768, fp32 in/out, bf16 MFMA internally.
//
// Round 21: dispatch-boundary reduction, correctness-safe. r20's fused pv
// failed again (2nd clean-audit failure) -> pv-fusion lane closed; revert to
// r19 exact (champion, 212.8us). Change: proj_q + proj_kv are INDEPENDENT
// (xb@wqt vs eb@wkt/wvt) -> merge into one 1024-block dispatch proj_all
// (block-uniform branch), removing one ~13us boundary.
//   - LDS: single 80KB carved array (union of both paths' layouts); statics
//     would sum to 136KB -> 1 blk/CU. q path grows 56->80KB but stays
//     2 blk/CU -> occupancy unchanged.
//   - Cores are byte-identical copies of the r19-verified bodies with LDS
//     arrays as pointer params. No sync/addressing/math changes.
//   - 1024 blocks = 2.0 even rounds at 2 blk/CU; kv offset 512 === 0 mod 8
//     so XCD pinning (p&7) is preserved for both halves.
// Everything else byte-identical to r19.
// ---------------------------------------------------------------------------

typedef __bf16 bf16x8 __attribute__((ext_vector_type(8)));
typedef float  f32x4  __attribute__((ext_vector_type(4)));

#define WAIT_VM8  __builtin_amdgcn_s_waitcnt(0x0F78)   // vmcnt(8), lgkm/exp nowait
#define WAIT_VM7  __builtin_amdgcn_s_waitcnt(0x0F77)   // vmcnt(7)
#define WAIT_VM10 __builtin_amdgcn_s_waitcnt(0x0F7A)   // vmcnt(10)
#define WAIT_VM0  __builtin_amdgcn_s_waitcnt(0x0F70)   // vmcnt(0)
#define BAR       __builtin_amdgcn_s_barrier()

__device__ __forceinline__ unsigned short f2bf(float f) {
    unsigned int u = __float_as_uint(f);
    u += 0x7fffu + ((u >> 16) & 1u);   // RNE; inputs are finite
    return (unsigned short)(u >> 16);
}

__device__ __forceinline__ void async_copy16(const void* g, void* s) {
    __builtin_amdgcn_global_load_lds(
        (const __attribute__((address_space(1))) void*)g,
        (__attribute__((address_space(3))) void*)s, 16, 0, 0);
}

// Block computes C[row0:row0+128, col0:col0+NB], NB in {96,128}.
// Ag = A + row0*K ([*,K] bf16 row-major); Bg = B^T + col0*K ([*,K]).
// Exactly one of Cf/Cb non-null. transC: store C^T as [b][H][S] (vt).
// Self-contained statics version (scores / pv / outproj).
template<int NB>
__device__ __forceinline__ void gemm_core(
    const unsigned short* __restrict__ Ag,
    const unsigned short* __restrict__ Bg,
    const int K,
    float* __restrict__ Cf, unsigned short* __restrict__ Cb,
    const long ldc, const int transC, const float* __restrict__ bias,
    const float scale, const long row0, const long col0)
{
    constexpr int NJ  = NB / 32;          // B col-frags per wave-half: 3 or 4
    constexpr int NBH = NB / 32;          // B staging insts: 3 or 4

    __shared__ __align__(16) unsigned short As0[8192];       // [128][64] swizzled
    __shared__ __align__(16) unsigned short As1[8192];
    __shared__ __align__(16) unsigned short Bs0[NB * 64];    // [NB][64] swizzled
    __shared__ __align__(16) unsigned short Bs1[NB * 64];

    const int tid  = threadIdx.x;
    const int lane = tid & 63;
    const int quad = lane >> 4;
    const int l16  = lane & 15;
    const int wv   = tid >> 6;
    const int wm   = (wv >> 1) * 64;
    const int wn   = (wv & 1) * (NB / 2);

    // staging: inst i covers row r = i*32 + (tid>>3), linear slot s = tid&7;
    // source k-chunk j = s ^ (r&7) = (tid&7)^((tid>>3)&7)  (i*32 === 0 mod 8).
    const int j8 = ((tid & 7) ^ ((tid >> 3) & 7)) * 8;     // src k-offset, elems
    const unsigned short* a_src = Ag + (long)(tid >> 3) * K + j8;
    const unsigned short* b_src = Bg + (long)(tid >> 3) * K + j8;
    const int dofs = tid * 8;

    f32x4 acc[4][NJ];
#pragma unroll
    for (int i = 0; i < 4; ++i)
#pragma unroll
        for (int j = 0; j < NJ; ++j)
            acc[i][j] = f32x4{0.f, 0.f, 0.f, 0.f};

    auto stage = [&](unsigned short* dA, unsigned short* dB, int k0) {
#pragma unroll
        for (int i = 0; i < 4; ++i)
            async_copy16(a_src + (long)(i * 32) * K + k0, &dA[i * 2048 + dofs]);
#pragma unroll
        for (int i = 0; i < NBH; ++i)
            async_copy16(b_src + (long)(i * 32) * K + k0, &dB[i * 2048 + dofs]);
    };

    auto compute = [&](const unsigned short* sA, const unsigned short* sB) {
#pragma unroll
        for (int h = 0; h < 2; ++h) {
            bf16x8 af[4], bf[NJ];
            const int sl = ((quad + h * 4) ^ (l16 & 7)) * 8;
#pragma unroll
            for (int i = 0; i < 4; ++i)
                af[i] = *(const bf16x8*)&sA[(wm + i * 16 + l16) * 64 + sl];
#pragma unroll
            for (int j = 0; j < NJ; ++j)
                bf[j] = *(const bf16x8*)&sB[(wn + j * 16 + l16) * 64 + sl];
#pragma unroll
            for (int i = 0; i < 4; ++i)
#pragma unroll
                for (int j = 0; j < NJ; ++j)
                    acc[i][j] = __builtin_amdgcn_mfma_f32_16x16x32_bf16(
                        af[i], bf[j], acc[i][j], 0, 0, 0);
        }
    };

    const int nk = K >> 6;            // 12 or 16: even, >= 4
    stage(As0, Bs0, 0);
    stage(As1, Bs1, 64);
    int k0 = 128;

    for (int t = 0; t < nk - 2; t += 2) {
        if constexpr (NB == 128) { WAIT_VM8; } else { WAIT_VM7; }
        BAR;
        compute(As0, Bs0);
        BAR;
        stage(As0, Bs0, k0); k0 += 64;

        if constexpr (NB == 128) { WAIT_VM8; } else { WAIT_VM7; }
        BAR;
        compute(As1, Bs1);
        BAR;
        stage(As1, Bs1, k0); k0 += 64;
    }
    if constexpr (NB == 128) { WAIT_VM8; } else { WAIT_VM7; }
    BAR;
    compute(As0, Bs0);
    WAIT_VM0; BAR;
    compute(As1, Bs1);

    // epilogue: C/D layout col=lane&15, row=quad*4+reg  [m89/m91 verified]
#pragma unroll
    for (int i = 0; i < 4; ++i) {
#pragma unroll
        for (int j = 0; j < NJ; ++j) {
            const long r0 = row0 + wm + i * 16 + quad * 4;
            const long c  = col0 + wn + j * 16 + l16;
            const float bb = bias ? bias[c] : 0.0f;
#pragma unroll
            for (int r = 0; r < 4; ++r) {
                const float v = acc[i][j][r] * scale + bb;
                const long rr = r0 + r;
                if (Cb) {
                    if (transC) {
                        Cb[((rr >> 10) * 768 + c) * 1024 + (rr & 1023)] = f2bf(v);
                    } else {
                        Cb[rr * ldc + c] = f2bf(v);
                    }
                } else {
                    Cf[rr * ldc + c] = v;
                }
            }
        }
    }
}

// ---------------------------------------------------------------------------
// Pointer-LDS copy of gemm_core<96> for the merged proj kernel (byte-identical
// body; LDS arrays passed in). Used only by proj_all's q path.
__device__ __forceinline__ void gemm_core96p(
    const unsigned short* __restrict__ Ag,
    const unsigned short* __restrict__ Bg,
    const int K,
    unsigned short* __restrict__ Cb,
    const float* __restrict__ bias,
    const long row0, const long col0,
    unsigned short* __restrict__ As0, unsigned short* __restrict__ As1,
    unsigned short* __restrict__ Bs0, unsigned short* __restrict__ Bs1)
{
    const int tid  = threadIdx.x;
    const int lane = tid & 63;
    const int quad = lane >> 4;
    const int l16  = lane & 15;
    const int wv   = tid >> 6;
    const int wm   = (wv >> 1) * 64;
    const int wn   = (wv & 1) * 48;

    const int j8 = ((tid & 7) ^ ((tid >> 3) & 7)) * 8;     // src k-offset, elems
    const unsigned short* a_src = Ag + (long)(tid >> 3) * K + j8;
    const unsigned short* b_src = Bg + (long)(tid >> 3) * K + j8;
    const int dofs = tid * 8;

    f32x4 acc[4][3];
#pragma unroll
    for (int i = 0; i < 4; ++i)
#pragma unroll
        for (int j = 0; j < 3; ++j)
            acc[i][j] = f32x4{0.f, 0.f, 0.f, 0.f};

    auto stage = [&](unsigned short* dA, unsigned short* dB, int k0) {
#pragma unroll
        for (int i = 0; i < 4; ++i)
            async_copy16(a_src + (long)(i * 32) * K + k0, &dA[i * 2048 + dofs]);
#pragma unroll
        for (int i = 0; i < 3; ++i)
            async_copy16(b_src + (long)(i * 32) * K + k0, &dB[i * 2048 + dofs]);
    };

    auto compute = [&](const unsigned short* sA, const unsigned short* sB) {
#pragma unroll
        for (int h = 0; h < 2; ++h) {
            bf16x8 af[4], bf[3];
            const int sl = ((quad + h * 4) ^ (l16 & 7)) * 8;
#pragma unroll
            for (int i = 0; i < 4; ++i)
                af[i] = *(const bf16x8*)&sA[(wm + i * 16 + l16) * 64 + sl];
#pragma unroll
            for (int j = 0; j < 3; ++j)
                bf[j] = *(const bf16x8*)&sB[(wn + j * 16 + l16) * 64 + sl];
#pragma unroll
            for (int i = 0; i < 4; ++i)
#pragma unroll
                for (int j = 0; j < 3; ++j)
                    acc[i][j] = __builtin_amdgcn_mfma_f32_16x16x32_bf16(
                        af[i], bf[j], acc[i][j], 0, 0, 0);
        }
    };

    const int nk = K >> 6;            // 12
    stage(As0, Bs0, 0);
    stage(As1, Bs1, 64);
    int k0 = 128;

    for (int t = 0; t < nk - 2; t += 2) {
        WAIT_VM7; BAR;
        compute(As0, Bs0);
        BAR;
        stage(As0, Bs0, k0); k0 += 64;

        WAIT_VM7; BAR;
        compute(As1, Bs1);
        BAR;
        stage(As1, Bs1, k0); k0 += 64;
    }
    WAIT_VM7; BAR;
    compute(As0, Bs0);
    WAIT_VM0; BAR;
    compute(As1, Bs1);

#pragma unroll
    for (int i = 0; i < 4; ++i) {
#pragma unroll
        for (int j = 0; j < 3; ++j) {
            const long r0 = row0 + wm + i * 16 + quad * 4;
            const long c  = col0 + wn + j * 16 + l16;
            const float bb = bias[c];
#pragma unroll
            for (int r = 0; r < 4; ++r)
                Cb[(r0 + r) * 768 + c] = f2bf(acc[i][j][r] + bb);
        }
    }
}

// ---------------------------------------------------------------------------
// Dual-B core for the k/v projections (r19-verified body; LDS via pointers).
// Stages A (eb strip) ONCE, two B panels, two acc sets. NB=96, K=768.
__device__ __forceinline__ void gemm_core_kv(
    const unsigned short* __restrict__ Ag,
    const unsigned short* __restrict__ Bk,
    const unsigned short* __restrict__ Bv,
    const float* __restrict__ bk, const float* __restrict__ bv,
    unsigned short* __restrict__ kout,
    unsigned short* __restrict__ vtout,
    const long row0, const long col0,
    unsigned short* __restrict__ As0, unsigned short* __restrict__ As1,
    unsigned short* __restrict__ Bk0, unsigned short* __restrict__ Bk1,
    unsigned short* __restrict__ Bv0, unsigned short* __restrict__ Bv1)
{
    constexpr int K = 768;

    const int tid  = threadIdx.x;
    const int lane = tid & 63;
    const int quad = lane >> 4;
    const int l16  = lane & 15;
    const int wv   = tid >> 6;
    const int wm   = (wv >> 1) * 64;
    const int wn   = (wv & 1) * 48;

    const int j8 = ((tid & 7) ^ ((tid >> 3) & 7)) * 8;
    const unsigned short* a_src  = Ag + (long)(tid >> 3) * K + j8;
    const unsigned short* bk_src = Bk + (long)(tid >> 3) * K + j8;
    const unsigned short* bv_src = Bv + (long)(tid >> 3) * K + j8;
    const int dofs = tid * 8;

    f32x4 acck[4][3], accv[4][3];
#pragma unroll
    for (int i = 0; i < 4; ++i)
#pragma unroll
        for (int j = 0; j < 3; ++j) {
            acck[i][j] = f32x4{0.f, 0.f, 0.f, 0.f};
            accv[i][j] = f32x4{0.f, 0.f, 0.f, 0.f};
        }

    auto stage = [&](unsigned short* dA, unsigned short* dK, unsigned short* dV,
                     int k0) {
#pragma unroll
        for (int i = 0; i < 4; ++i)
            async_copy16(a_src + (long)(i * 32) * K + k0, &dA[i * 2048 + dofs]);
#pragma unroll
        for (int i = 0; i < 3; ++i)
            async_copy16(bk_src + (long)(i * 32) * K + k0, &dK[i * 2048 + dofs]);
#pragma unroll
        for (int i = 0; i < 3; ++i)
            async_copy16(bv_src + (long)(i * 32) * K + k0, &dV[i * 2048 + dofs]);
    };

    auto compute = [&](const unsigned short* sA, const unsigned short* sK,
                       const unsigned short* sV) {
#pragma unroll
        for (int h = 0; h < 2; ++h) {
            bf16x8 af[4], bkf[3], bvf[3];
            const int sl = ((quad + h * 4) ^ (l16 & 7)) * 8;
#pragma unroll
            for (int i = 0; i < 4; ++i)
                af[i] = *(const bf16x8*)&sA[(wm + i * 16 + l16) * 64 + sl];
#pragma unroll
            for (int j = 0; j < 3; ++j) {
                bkf[j] = *(const bf16x8*)&sK[(wn + j * 16 + l16) * 64 + sl];
                bvf[j] = *(const bf16x8*)&sV[(wn + j * 16 + l16) * 64 + sl];
            }
#pragma unroll
            for (int i = 0; i < 4; ++i)
#pragma unroll
                for (int j = 0; j < 3; ++j) {
                    acck[i][j] = __builtin_amdgcn_mfma_f32_16x16x32_bf16(
                        af[i], bkf[j], acck[i][j], 0, 0, 0);
                    accv[i][j] = __builtin_amdgcn_mfma_f32_16x16x32_bf16(
                        af[i], bvf[j], accv[i][j], 0, 0, 0);
                }
        }
    };

    const int nk = K >> 6;            // 12
    stage(As0, Bk0, Bv0, 0);
    stage(As1, Bk1, Bv1, 64);
    int k0 = 128;

    for (int t = 0; t < nk - 2; t += 2) {
        WAIT_VM10; BAR;
        compute(As0, Bk0, Bv0);
        BAR;
        stage(As0, Bk0, Bv0, k0); k0 += 64;

        WAIT_VM10; BAR;
        compute(As1, Bk1, Bv1);
        BAR;
        stage(As1, Bk1, Bv1, k0); k0 += 64;
    }
    WAIT_VM10; BAR;
    compute(As0, Bk0, Bv0);
    WAIT_VM0; BAR;
    compute(As1, Bk1, Bv1);

#pragma unroll
    for (int i = 0; i < 4; ++i) {
#pragma unroll
        for (int j = 0; j < 3; ++j) {
            const long r0 = row0 + wm + i * 16 + quad * 4;
            const long c  = col0 + wn + j * 16 + l16;
            const float bbk = bk[c], bbv = bv[c];
#pragma unroll
            for (int r = 0; r < 4; ++r) {
                const long rr = r0 + r;
                kout[rr * 768 + c] = f2bf(acck[i][j][r] + bbk);
                vtout[((rr >> 10) * 768 + c) * 1024 + (rr & 1023)] =
                    f2bf(accv[i][j][r] + bbv);
            }
        }
    }
}

// ---------------------------------------------------------------------------
// XCD-locality mapping (HW round-robins consecutive blockIdx.x over 8 XCDs).

// Merged q + kv projections: blocks [0,512) = q, [512,1024) = kv.
// One 80KB carved LDS array (union of both layouts); both paths 2 blocks/CU.
__global__ __launch_bounds__(256, 2) void proj_all(
    const unsigned short* __restrict__ xb, const unsigned short* __restrict__ eb,
    const unsigned short* __restrict__ wqt, const unsigned short* __restrict__ wkt,
    const unsigned short* __restrict__ wvt,
    const float* __restrict__ bq, const float* __restrict__ bk,
    const float* __restrict__ bv,
    unsigned short* __restrict__ q, unsigned short* __restrict__ k,
    unsigned short* __restrict__ vt)
{
    __shared__ __align__(16) unsigned short smem[40960];   // 80 KB
    const int p0 = blockIdx.x;
    if (p0 < 512) {
        const int g = p0 & 7, m = p0 >> 3;    // m in [0,64)
        const long row0 = (long)(g * 8 + (m & 7)) * 128;
        const long col0 = (long)(m >> 3) * 96;
        gemm_core96p(xb + row0 * 768, wqt + col0 * 768, 768, q, bq, row0, col0,
                     smem, smem + 8192, smem + 16384, smem + 22528);
    } else {
        const int p = p0 - 512;               // 512 === 0 mod 8: XCD map intact
        const int g = p & 7, m = p >> 3;
        const long row0 = (long)(g * 8 + (m & 7)) * 128;
        const long col0 = (long)(m >> 3) * 96;
        gemm_core_kv(eb + row0 * 768, wkt + col0 * 768, wvt + col0 * 768,
                     bk, bv, k, vt, row0, col0,
                     smem, smem + 8192, smem + 16384, smem + 22528,
                     smem + 28672, smem + 34816);
    }
}

__global__ __launch_bounds__(256, 2) void scores_gemm(
    const unsigned short* __restrict__ q, const unsigned short* __restrict__ k,
    float* __restrict__ sc, float scale)
{
    const int p = blockIdx.x;                 // [0,512): batch pinned to XCD
    const long b = p & 7;
    const int m  = p >> 3;                    // [0,64)
    const long row0 = (long)(m & 7) * 128;
    const long col0 = (long)(m >> 3) * 128;
    gemm_core<128>(q + (b * 1024 + row0) * 768, k + b * 786432 + col0 * 768, 768,
                   sc + b * 1048576, nullptr, 1024, 0, nullptr, scale, row0, col0);
}

__global__ __launch_bounds__(256, 2) void pv_gemm(
    const unsigned short* __restrict__ p_, const unsigned short* __restrict__ vt,
    unsigned short* __restrict__ ao)
{
    const int p = blockIdx.x;                 // [0,512): batch pinned to XCD
    const long b = p & 7;
    const int m  = p >> 3;                    // [0,64)
    const long row0 = (long)(m & 7) * 128;
    const long col0 = (long)(m >> 3) * 96;    // 8 col-tiles of 96 = 768
    gemm_core<96>(p_ + (b * 1024 + row0) * 1024, vt + b * 786432 + col0 * 1024, 1024,
                  nullptr, ao + b * 786432, 768, 0, nullptr, 1.0f, row0, col0);
}

__global__ __launch_bounds__(256, 2) void outproj_gemm(
    const unsigned short* __restrict__ ao, const unsigned short* __restrict__ wpt,
    float* __restrict__ out, const float* __restrict__ bp)
{
    const int p = blockIdx.x;                 // [0,512)
    const int g = p & 7, m = p >> 3;          // m in [0,64)
    const long row0 = (long)(g * 8 + (m & 7)) * 128;
    const long col0 = (long)(m >> 3) * 96;
    gemm_core<96>(ao + row0 * 768, wpt + col0 * 768, 768,
                  out, nullptr, 768, 0, bp, 1.0f, row0, col0);
}

// ---------------------------------------------------------------------------
// prep: fp32->bf16 conversion of x/enc (blocks 0..12287) + 32x32 bf16
// transposes of the four weights (blocks 12288..14591).

__global__ __launch_bounds__(256) void prep(
    const float* __restrict__ x, const float* __restrict__ enc,
    unsigned short* __restrict__ xb, unsigned short* __restrict__ eb,
    const float* __restrict__ w0, const float* __restrict__ w1,
    const float* __restrict__ w2, const float* __restrict__ w3,
    unsigned short* __restrict__ o0, unsigned short* __restrict__ o1,
    unsigned short* __restrict__ o2, unsigned short* __restrict__ o3)
{
    __shared__ float t[32][33];
    const int bx = blockIdx.x;
    if (bx < 12288) {
        const int i = bx * 256 + threadIdx.x;   // float4 index
        const bool second = (i >= 1572864);
        const int idx = second ? i - 1572864 : i;
        const float4 v = second ? ((const float4*)enc)[idx] : ((const float4*)x)[idx];
        ushort4 o;
        o.x = f2bf(v.x); o.y = f2bf(v.y); o.z = f2bf(v.z); o.w = f2bf(v.w);
        if (second) ((ushort4*)eb)[idx] = o;
        else        ((ushort4*)xb)[idx] = o;
        return;
    }
    const int z  = bx - 12288;                  // 0..2303
    const int wi = z / 576;                     // which weight
    const int tt = z % 576;                     // 24x24 tiles
    const float* w; unsigned short* o;
    switch (wi) {
        case 0:  w = w0; o = o0; break;
        case 1:  w = w1; o = o1; break;
        case 2:  w = w2; o = o2; break;
        default: w = w3; o = o3; break;
    }
    const int tx = threadIdx.x & 31;
    const int ty = threadIdx.x >> 5;            // 0..7
    const int k0 = (tt % 24) * 32;
    const int n0 = (tt / 24) * 32;
#pragma unroll
    for (int i = 0; i < 4; ++i)
        t[ty + i * 8][tx] = w[(long)(k0 + ty + i * 8) * 768 + n0 + tx];
    __syncthreads();
#pragma unroll
    for (int i = 0; i < 4; ++i)
        o[(long)(n0 + ty + i * 8) * 768 + k0 + tx] = f2bf(t[tx][ty + i * 8]);
}

__global__ __launch_bounds__(256) void softmax_rows(
    const float* __restrict__ S, unsigned short* __restrict__ P)
{
    const long row = blockIdx.x;                 // 8192 rows of 1024
    const float* s = S + row * 1024;
    unsigned short* p = P + row * 1024;
    const int tid  = threadIdx.x;
    const int lane = tid & 63;
    const int wave = tid >> 6;

    float4 v = ((const float4*)s)[tid];
    float m = fmaxf(fmaxf(v.x, v.y), fmaxf(v.z, v.w));
#pragma unroll
    for (int off = 32; off > 0; off >>= 1)
        m = fmaxf(m, __shfl_xor(m, off));
    __shared__ float redm[4], reds[4];
    if (lane == 0) redm[wave] = m;
    __syncthreads();
    m = fmaxf(fmaxf(redm[0], redm[1]), fmaxf(redm[2], redm[3]));

    const float e0 = __expf(v.x - m), e1 = __expf(v.y - m);
    const float e2 = __expf(v.z - m), e3 = __expf(v.w - m);
    float sum = e0 + e1 + e2 + e3;
#pragma unroll
    for (int off = 32; off > 0; off >>= 1)
        sum += __shfl_xor(sum, off);
    if (lane == 0) reds[wave] = sum;
    __syncthreads();
    const float inv = 1.0f / (reds[0] + reds[1] + reds[2] + reds[3]);

    ushort4 o;
    o.x = f2bf(e0 * inv); o.y = f2bf(e1 * inv);
    o.z = f2bf(e2 * inv); o.w = f2bf(e3 * inv);
    ((ushort4*)p)[tid] = o;
}

// ---------------------------------------------------------------------------

extern "C" void kernel_launch(void* const* d_in, const int* in_sizes, int n_in,
                              void* d_out, int out_size, void* d_ws, size_t ws_size,
                              hipStream_t stream) {
    const float* x   = (const float*)d_in[0];
    const float* enc = (const float*)d_in[1];
    const float* Wq  = (const float*)d_in[2];
    const float* bq  = (const float*)d_in[3];
    const float* Wk  = (const float*)d_in[4];
    const float* bk  = (const float*)d_in[5];
    const float* Wv  = (const float*)d_in[6];
    const float* bv  = (const float*)d_in[7];
    const float* Wp  = (const float*)d_in[8];
    const float* bp  = (const float*)d_in[9];
    float* out = (float*)d_out;

    // workspace layout (bytes); peak need ~101.2 MB
    char* ws = (char*)d_ws;
    unsigned short* xb  = (unsigned short*)(ws + 0);         // 12582912
    unsigned short* eb  = (unsigned short*)(ws + 12582912);  // 12582912
    unsigned short* q   = (unsigned short*)(ws + 25165824);  // 12582912
    unsigned short* k   = (unsigned short*)(ws + 37748736);  // 12582912
    unsigned short* vt  = (unsigned short*)(ws + 50331648);  // 12582912 [B][H][S]
    unsigned short* wqt = (unsigned short*)(ws + 62914560);  // 1179648
    unsigned short* wkt = (unsigned short*)(ws + 64094208);  // 1179648
    unsigned short* wvt = (unsigned short*)(ws + 65273856);  // 1179648
    unsigned short* wpt = (unsigned short*)(ws + 66453504);  // 1179648
    float*          sc  = (float*)(ws + 67633152);           // 33554432 fp32 scores
    unsigned short* p   = (unsigned short*)(ws + 0);         // 16777216, overlays xb/eb (dead)
    unsigned short* ao  = (unsigned short*)(ws + 67633152);  // 12582912, overlays sc (dead)

    const float scale = 0.03608439182435161f;  // 1/sqrt(768)

    // 1. prep: fp32->bf16 inputs + W^T bf16 (fused)
    prep<<<14592, 256, 0, stream>>>(x, enc, xb, eb, Wq, Wk, Wv, Wp,
                                    wqt, wkt, wvt, wpt);

    // 2. q + kv projections in ONE dispatch: 1024 blocks = 2.0 even rounds
    proj_all<<<1024, 256, 0, stream>>>(xb, eb, wqt, wkt, wvt,
                                       bq, bk, bv, q, k, vt);

    // 3. scores = q k^T * scale (fp32): 128x128, 512 blocks (1.0 round)
    scores_gemm<<<512, 256, 0, stream>>>(q, k, sc, scale);

    // 4. softmax rows -> bf16 P
    softmax_rows<<<8192, 256, 0, stream>>>(sc, p);

    // 5. ao = P @ V: 128x96, 512 blocks (1.0 round)
    pv_gemm<<<512, 256, 0, stream>>>(p, vt, ao);

    // 6. out = ao @ Wp + bp: 128x96, 512 blocks (1.0 round)
    outproj_gemm<<<512, 256, 0, stream>>>(ao, wpt, out, bp);
}